// Round 8
// baseline (741.571 us; speedup 1.0000x reference)
//
#include <hip/hip_runtime.h>
#include <stdint.h>

// ---------------------------------------------------------------------------
// RichAttention: out = softmax(QK^T - w*cdist(coords)) @ V, attn also output.
// B=8, S=2048, H=768, fp32 in/out.
// R8 = R7 with:
//   - k_proj replaced by k_proj8p: same proven 8-phase 256^2 schedule as
//     k_scores8p (NT=36 virtual tiles for Q/K 3-term, NT=12 for V).
//   - XCD-aware bijective block swizzle on k_scores8p (one batch per XCD)
//     and k_pv16.
// ---------------------------------------------------------------------------

typedef _Float16 half8 __attribute__((ext_vector_type(8)));
typedef _Float16 half4v __attribute__((ext_vector_type(4)));
typedef float f32x4 __attribute__((ext_vector_type(4)));

#define DEVI static __device__ __forceinline__

constexpr int B_ = 8, S_ = 2048, H_ = 768;
constexpr long NX = (long)B_ * S_ * H_;   // 12,582,912
constexpr long NW = (long)H_ * H_;        // 589,824
constexpr long ATT = (long)B_ * S_ * S_;  // 33,554,432

// ---- async global->LDS, 16B per lane --------------------------------------
DEVI void glds16(const void* g, void* l) {
  __builtin_amdgcn_global_load_lds(
      (const __attribute__((address_space(1))) uint32_t*)g,
      (__attribute__((address_space(3))) uint32_t*)l, 16, 0, 0);
}

// Stage a [128][32]-fp16 tile (8KB). LDS slot (r,c) holds global chunk
// c ^ ((r>>1)&3). 256 threads x 2 units.
DEVI void stage_tile(const _Float16* gbase, int rowStride, _Float16* lds, int tid) {
#pragma unroll
  for (int seg = 0; seg < 2; ++seg) {
    int u = seg * 256 + tid;
    int r = u >> 2, c = u & 3;
    int sc = c ^ ((r >> 1) & 3);
    glds16(gbase + (long)r * rowStride + sc * 8, lds + ((u & ~63) << 3));
  }
}

// MFMA 16x16x32 A/B fragment read (undoes the chunk swizzle).
DEVI half8 frag(const _Float16* lds, int m0, int lane) {
  int row = m0 + (lane & 15);
  int c = (lane >> 4) ^ ((row >> 1) & 3);
  return *(const half8*)(lds + row * 32 + c * 8);
}

// ---------------------------------------------------------------------------
// K0: split. Xq,Xk -> hi/lo; Xv -> hi only; Wq,Wk -> hi/lo; Wv -> hi only.
// ---------------------------------------------------------------------------
__global__ __launch_bounds__(256) void k_split(
    const float* __restrict__ xq, const float* __restrict__ xk,
    const float* __restrict__ xv, const float* __restrict__ wq,
    const float* __restrict__ wk, const float* __restrict__ wv,
    _Float16* __restrict__ dst) {
  const long NX4 = NX / 4, NW4 = NW / 4, TOT = 3 * NX4 + 3 * NW4;
  for (long u = (long)blockIdx.x * blockDim.x + threadIdx.x; u < TOT;
       u += (long)gridDim.x * blockDim.x) {
    const float4* src;
    _Float16 *dh, *dl;
    bool wantLo = true;
    long idx;
    if (u < 3 * NX4) {
      int z = (u >= 2 * NX4) ? 2 : (u >= NX4) ? 1 : 0;
      idx = u - (long)z * NX4;
      src = (const float4*)(z == 0 ? xq : z == 1 ? xk : xv);
      dh = dst + (long)z * 2 * NX;
      dl = dh + NX;
      wantLo = (z < 2);
    } else {
      long t = u - 3 * NX4;
      int z = (t >= 2 * NW4) ? 2 : (t >= NW4) ? 1 : 0;
      idx = t - (long)z * NW4;
      src = (const float4*)(z == 0 ? wq : z == 1 ? wk : wv);
      dh = dst + 5 * NX + (long)z * 2 * NW;
      dl = dh + NW;
      wantLo = (z < 2);
    }
    float4 x = src[idx];
    half4v hi, lo;
    hi[0] = (_Float16)x.x; lo[0] = (_Float16)(x.x - (float)hi[0]);
    hi[1] = (_Float16)x.y; lo[1] = (_Float16)(x.y - (float)hi[1]);
    hi[2] = (_Float16)x.z; lo[2] = (_Float16)(x.z - (float)hi[2]);
    hi[3] = (_Float16)x.w; lo[3] = (_Float16)(x.w - (float)hi[3]);
    *(half4v*)(dh + idx * 4) = hi;
    if (wantLo) *(half4v*)(dl + idx * 4) = lo;
  }
}

// ---------------------------------------------------------------------------
// K1 (R8): projections Y = X @ W^T + b, 8-phase 256^2 schedule (same wait
// algebra as k_scores8p). z=0: Q (hi/lo out), z=1: K (hi/lo out), z=2: V ->
// transposed vT. Virtual-K ko-major: z<2: NT=36 (12 ko x 3 terms
// (Xh,Wh),(Xh,Wl),(Xl,Wh)); z=2: NT=12 (Xh,Wh only).
// Grid dim3(3,3,64): x=ntw, y=z (fast -> long/short blocks interleave), z=mt.
// ---------------------------------------------------------------------------
__global__ __launch_bounds__(512, 2) void k_proj8p(
    const _Float16* __restrict__ scratch, const float* __restrict__ bq,
    const float* __restrict__ bk, const float* __restrict__ bv,
    _Float16* __restrict__ qh, _Float16* __restrict__ ql,
    _Float16* __restrict__ kh, _Float16* __restrict__ kl,
    _Float16* __restrict__ vT) {
  const int ntw = blockIdx.x, z = blockIdx.y, mt = blockIdx.z;
  const int tid = threadIdx.x, lane = tid & 63, wid = tid >> 6;
  const int wr = wid >> 2, wc = wid & 3;  // 2x4 waves, each 128x64 out
  const bool full = (z < 2);
  const int NT = full ? 36 : 12;

  const _Float16* Ah = scratch + (long)z * 2 * NX;  // z=2 -> 4*NX (hi only)
  const _Float16* Al = Ah + NX;
  const _Float16* Bh = scratch + 5 * NX + (long)z * 2 * NW;
  const _Float16* Bl = Bh + NW;
  const float* bias = (z == 0) ? bq : (z == 1) ? bk : bv;

  __shared__ _Float16 lds[2][2][2][8192];  // [slot][khalf][A,B][256*32]

  const long aoff = (long)(mt * 256) * H_;
  const long boff = (long)(ntw * 256) * H_;

  long goff[2];
  int loff[2];
#pragma unroll
  for (int seg = 0; seg < 2; ++seg) {
    int u = seg * 512 + tid;
    int r = u >> 2, c = u & 3;
    int sc = c ^ ((r >> 1) & 3);
    goff[seg] = (long)r * H_ + sc * 8;
    loff[seg] = (u & ~63) << 3;
  }

  f32x4 acc[8][4] = {};

  auto stage_half = [&](int h) {
    int th = h >> 2, kind = h & 3;
    int khf = kind >> 1, mx = kind & 1;
    int term, ko;
    if (full) { term = th % 3; ko = (th / 3) * 64 + khf * 32; }
    else { term = 0; ko = th * 64 + khf * 32; }
    const _Float16* src = mx ? ((term == 1 ? Bl : Bh) + boff + ko)
                             : ((term == 2 ? Al : Ah) + aoff + ko);
    _Float16* dst = &lds[th & 1][khf][mx][0];
    glds16(src + goff[0], dst + loff[0]);
    glds16(src + goff[1], dst + loff[1]);
  };

  half8 bf[4];

  auto phase = [&](int slot, int kh2, int mh, int hst, int vm) {
    const _Float16* A = &lds[slot][kh2][0][0];
    const _Float16* Bt = &lds[slot][kh2][1][0];
    half8 af[4];
    if (mh == 0) {
#pragma unroll
      for (int j = 0; j < 4; ++j) bf[j] = frag(Bt, wc * 64 + j * 16, lane);
    }
#pragma unroll
    for (int i = 0; i < 4; ++i)
      af[i] = frag(A, wr * 128 + mh * 64 + i * 16, lane);
    if (hst >= 0) stage_half(hst);
    if (vm == 6) asm volatile("s_waitcnt vmcnt(6)" ::: "memory");
    else if (vm == 0) asm volatile("s_waitcnt vmcnt(0)" ::: "memory");
    __builtin_amdgcn_s_barrier();
    asm volatile("s_waitcnt lgkmcnt(0)" ::: "memory");
    __builtin_amdgcn_sched_barrier(0);
    __builtin_amdgcn_s_setprio(1);
#pragma unroll
    for (int i = 0; i < 4; ++i)
#pragma unroll
      for (int j = 0; j < 4; ++j)
        acc[mh * 4 + i][j] = __builtin_amdgcn_mfma_f32_16x16x32_f16(
            af[i], bf[j], acc[mh * 4 + i][j], 0, 0, 0);
    __builtin_amdgcn_s_setprio(0);
    asm volatile("" ::: "memory");
    __builtin_amdgcn_s_barrier();
  };

  // prologue: stage halves 0..6 (D=7); vmcnt(6) -> tile 0's 4 halves landed
#pragma unroll
  for (int h = 0; h < 7; ++h) stage_half(h);
  asm volatile("s_waitcnt vmcnt(6)" ::: "memory");
  __builtin_amdgcn_s_barrier();

#pragma unroll 1
  for (int t = 0; t < NT - 2; ++t) {
    const int slot = t & 1, P = 4 * t;
    phase(slot, 0, 0, P + 7, -1);
    phase(slot, 0, 1, P + 8, -1);
    phase(slot, 1, 0, P + 9, -1);
    phase(slot, 1, 1, P + 10, 6);
  }
  // tile NT-2 (slot 0): stage final half, drain at last phase
  phase(0, 0, 0, 4 * NT - 1, -1);
  phase(0, 0, 1, -1, -1);
  phase(0, 1, 0, -1, -1);
  phase(0, 1, 1, -1, 0);
  // tile NT-1 (slot 1): all landed
  phase(1, 0, 0, -1, -1);
  phase(1, 0, 1, -1, -1);
  phase(1, 1, 0, -1, -1);
  phase(1, 1, 1, -1, -1);

  // epilogue
  _Float16* oh = (z == 0) ? qh : kh;
  _Float16* ol = (z == 0) ? ql : kl;
#pragma unroll
  for (int mi = 0; mi < 8; ++mi) {
    int m_t = wr * 128 + mi * 16 + ((lane >> 4) << 2);
#pragma unroll
    for (int j = 0; j < 4; ++j) {
      int n_t = wc * 64 + j * 16 + (lane & 15);
      int gn = ntw * 256 + n_t;
      float bs = bias[gn];
      if (full) {
#pragma unroll
        for (int r = 0; r < 4; ++r) {
          long gm = (long)mt * 256 + m_t + r;
          float y = acc[mi][j][r] + bs;
          _Float16 hi = (_Float16)y;
          oh[gm * H_ + gn] = hi;
          ol[gm * H_ + gn] = (_Float16)(y - (float)hi);
        }
      } else {
        int gmI = mt * 256 + m_t;
        int bb = gmI >> 11, t0 = gmI & 2047;
        half4v pk;
#pragma unroll
        for (int r = 0; r < 4; ++r) pk[r] = (_Float16)(acc[mi][j][r] + bs);
        *(half4v*)&vT[((long)bb * H_ + gn) * S_ + t0] = pk;
      }
    }
  }
}

// ---------------------------------------------------------------------------
// K2 (R7+swizzle): raw scores = q.k (3-term) - w*dist. 8-phase schedule.
// XCD swizzle: 512 blocks -> each XCD gets one batch (bijective, 512%8==0).
// ---------------------------------------------------------------------------
__global__ __launch_bounds__(512, 2) void k_scores8p(
    const _Float16* __restrict__ qh, const _Float16* __restrict__ ql,
    const _Float16* __restrict__ kh_, const _Float16* __restrict__ kl_,
    const float* __restrict__ coords, const float* __restrict__ sw,
    float* __restrict__ attn) {
  int bid = blockIdx.x + 8 * blockIdx.y + 64 * blockIdx.z;
  int swz = (bid & 7) * 64 + (bid >> 3);
  const int nt = swz & 7, mt = (swz >> 3) & 7, b = swz >> 6;
  const int tid = threadIdx.x, lane = tid & 63, wid = tid >> 6;
  const int wr = wid >> 2, wc = wid & 3;

  __shared__ _Float16 lds[2][2][2][8192];
  __shared__ float cco[4][256];

  if (tid < 256) {
    long gi = (long)b * S_ + mt * 256 + tid;
    cco[0][tid] = coords[gi * 2 + 0];
    cco[1][tid] = coords[gi * 2 + 1];
  } else {
    int t = tid - 256;
    long gj = (long)b * S_ + nt * 256 + t;
    cco[2][t] = coords[gj * 2 + 0];
    cco[3][t] = coords[gj * 2 + 1];
  }
  const float w = sw[0];

  const long aoff = ((long)b * S_ + mt * 256) * H_;
  const long boff = ((long)b * S_ + nt * 256) * H_;

  long goff[2];
  int loff[2];
#pragma unroll
  for (int seg = 0; seg < 2; ++seg) {
    int u = seg * 512 + tid;
    int r = u >> 2, c = u & 3;
    int sc = c ^ ((r >> 1) & 3);
    goff[seg] = (long)r * H_ + sc * 8;
    loff[seg] = (u & ~63) << 3;
  }

  f32x4 acc[8][4] = {};

  auto stage_half = [&](int h) {
    int th = h >> 2, kind = h & 3;
    int khf = kind >> 1, mx = kind & 1;
    int term = th % 3;
    long ko = (long)(th / 3) * 64 + khf * 32;
    const _Float16* src = mx ? ((term == 1 ? kl_ : kh_) + boff + ko)
                             : ((term == 2 ? ql : qh) + aoff + ko);
    _Float16* dst = &lds[th & 1][khf][mx][0];
    glds16(src + goff[0], dst + loff[0]);
    glds16(src + goff[1], dst + loff[1]);
  };

  half8 bf[4];

  auto phase = [&](int slot, int kh2, int mh, int hst, int vm) {
    const _Float16* A = &lds[slot][kh2][0][0];
    const _Float16* Bt = &lds[slot][kh2][1][0];
    half8 af[4];
    if (mh == 0) {
#pragma unroll
      for (int j = 0; j < 4; ++j) bf[j] = frag(Bt, wc * 64 + j * 16, lane);
    }
#pragma unroll
    for (int i = 0; i < 4; ++i)
      af[i] = frag(A, wr * 128 + mh * 64 + i * 16, lane);
    if (hst >= 0) stage_half(hst);
    if (vm == 6) asm volatile("s_waitcnt vmcnt(6)" ::: "memory");
    else if (vm == 0) asm volatile("s_waitcnt vmcnt(0)" ::: "memory");
    __builtin_amdgcn_s_barrier();
    asm volatile("s_waitcnt lgkmcnt(0)" ::: "memory");
    __builtin_amdgcn_sched_barrier(0);
    __builtin_amdgcn_s_setprio(1);
#pragma unroll
    for (int i = 0; i < 4; ++i)
#pragma unroll
      for (int j = 0; j < 4; ++j)
        acc[mh * 4 + i][j] = __builtin_amdgcn_mfma_f32_16x16x32_f16(
            af[i], bf[j], acc[mh * 4 + i][j], 0, 0, 0);
    __builtin_amdgcn_s_setprio(0);
    asm volatile("" ::: "memory");
    __builtin_amdgcn_s_barrier();
  };

#pragma unroll
  for (int h = 0; h < 7; ++h) stage_half(h);
  asm volatile("s_waitcnt vmcnt(6)" ::: "memory");
  __builtin_amdgcn_s_barrier();

#pragma unroll 1
  for (int t = 0; t < 34; ++t) {
    const int slot = t & 1, P = 4 * t;
    phase(slot, 0, 0, P + 7, -1);
    phase(slot, 0, 1, P + 8, -1);
    phase(slot, 1, 0, P + 9, -1);
    phase(slot, 1, 1, P + 10, 6);
  }
  phase(0, 0, 0, 143, -1);
  phase(0, 0, 1, -1, -1);
  phase(0, 1, 0, -1, -1);
  phase(0, 1, 1, -1, 0);
  phase(1, 0, 0, -1, -1);
  phase(1, 0, 1, -1, -1);
  phase(1, 1, 0, -1, -1);
  phase(1, 1, 1, -1, -1);

#pragma unroll
  for (int mi = 0; mi < 8; ++mi) {
    int m_t = wr * 128 + mi * 16 + ((lane >> 4) << 2);
#pragma unroll
    for (int j = 0; j < 4; ++j) {
      int n_t = wc * 64 + j * 16 + (lane & 15);
      float cjx = cco[2][n_t], cjy = cco[3][n_t];
      long rowbase = ((long)b * S_ + mt * 256 + m_t) * S_ + nt * 256 + n_t;
#pragma unroll
      for (int r = 0; r < 4; ++r) {
        float dx = cco[0][m_t + r] - cjx;
        float dy = cco[1][m_t + r] - cjy;
        float d = sqrtf(fmaxf(fmaf(dx, dx, dy * dy), 1e-12f));
        attn[rowbase + (long)r * S_] = acc[mi][j][r] - w * d;
      }
    }
  }
}

// ---------------------------------------------------------------------------
// K2b: row softmax in place (fp32) + normalized fp16 copy for k_pv16.
// ---------------------------------------------------------------------------
__global__ __launch_bounds__(256) void k_rowsoft(float* __restrict__ attn,
                                                 _Float16* __restrict__ a16) {
  const int wid = threadIdx.x >> 6, lane = threadIdx.x & 63;
  long row = (long)blockIdx.x * 4 + wid;
  float* p = attn + row * S_;
  _Float16* p16 = a16 + row * S_;
  float4 v[8];
#pragma unroll
  for (int i = 0; i < 8; ++i) v[i] = ((const float4*)p)[i * 64 + lane];
  float m = -3.4e38f;
#pragma unroll
  for (int i = 0; i < 8; ++i)
    m = fmaxf(m, fmaxf(fmaxf(v[i].x, v[i].y), fmaxf(v[i].z, v[i].w)));
#pragma unroll
  for (int o = 32; o > 0; o >>= 1) m = fmaxf(m, __shfl_xor(m, o));
  float l = 0.f;
#pragma unroll
  for (int i = 0; i < 8; ++i) {
    v[i].x = __expf(v[i].x - m);
    v[i].y = __expf(v[i].y - m);
    v[i].z = __expf(v[i].z - m);
    v[i].w = __expf(v[i].w - m);
    l += (v[i].x + v[i].y) + (v[i].z + v[i].w);
  }
#pragma unroll
  for (int o = 32; o > 0; o >>= 1) l += __shfl_xor(l, o);
  const float rl = 1.0f / l;
#pragma unroll
  for (int i = 0; i < 8; ++i) {
    v[i].x *= rl; v[i].y *= rl; v[i].z *= rl; v[i].w *= rl;
    ((float4*)p)[i * 64 + lane] = v[i];
    half4v h = {(_Float16)v[i].x, (_Float16)v[i].y, (_Float16)v[i].z,
                (_Float16)v[i].w};
    ((half4v*)p16)[i * 64 + lane] = h;
  }
}

// ---------------------------------------------------------------------------
// K3: out = a16 @ vT^T. Pure global_load_lds fp16 pipeline, K=2048.
// XCD swizzle: 768 blocks -> 96/XCD = one batch per XCD (768%8==0).
// ---------------------------------------------------------------------------
__global__ __launch_bounds__(256, 2) void k_pv16(
    const _Float16* __restrict__ a16, const _Float16* __restrict__ vT,
    float* __restrict__ outp) {
  int bid = blockIdx.x + 6 * blockIdx.y + 96 * blockIdx.z;
  int swz = (bid & 7) * 96 + (bid >> 3);
  const int nt = swz % 6, mt = (swz / 6) & 15, b = swz / 96;
  const int tid = threadIdx.x, lane = tid & 63, wid = tid >> 6;
  const int wm = (wid >> 1) * 64, wn = (wid & 1) * 64;
  __shared__ _Float16 sm[2][2][4096];
  f32x4 acc[4][4] = {};
  const _Float16* Ab = a16 + ((long)b * S_ + mt * 128) * S_;
  const _Float16* Bb = vT + ((long)b * H_ + nt * 128) * S_;

  stage_tile(Ab, S_, sm[0][0], tid);
  stage_tile(Bb, S_, sm[0][1], tid);
  __syncthreads();

  int cur = 0;
  for (int kk = 0; kk < 64; ++kk) {
    if (kk + 1 < 64) {
      stage_tile(Ab + (kk + 1) * 32, S_, sm[cur ^ 1][0], tid);
      stage_tile(Bb + (kk + 1) * 32, S_, sm[cur ^ 1][1], tid);
    }
    half8 ah[4], bh[4];
#pragma unroll
    for (int i = 0; i < 4; ++i) ah[i] = frag(sm[cur][0], wm + i * 16, lane);
#pragma unroll
    for (int j = 0; j < 4; ++j) bh[j] = frag(sm[cur][1], wn + j * 16, lane);
#pragma unroll
    for (int i = 0; i < 4; ++i)
#pragma unroll
      for (int j = 0; j < 4; ++j)
        acc[i][j] = __builtin_amdgcn_mfma_f32_16x16x32_f16(ah[i], bh[j],
                                                           acc[i][j], 0, 0, 0);
    __syncthreads();
    cur ^= 1;
  }

#pragma unroll
  for (int i = 0; i < 4; ++i) {
    int m_t = wm + i * 16 + ((lane >> 4) << 2);
#pragma unroll
    for (int j = 0; j < 4; ++j) {
      int n_t = wn + j * 16 + (lane & 15);
      int h = nt * 128 + n_t;
      long rowbase = (long)b * S_ + mt * 128 + m_t;
#pragma unroll
      for (int r = 0; r < 4; ++r) outp[(rowbase + r) * H_ + h] = acc[i][j][r];
    }
  }
}

// ---------------------------------------------------------------------------
extern "C" void kernel_launch(void* const* d_in, const int* in_sizes, int n_in,
                              void* d_out, int out_size, void* d_ws,
                              size_t ws_size, hipStream_t stream) {
  const float* xq = (const float*)d_in[0];
  const float* xk = (const float*)d_in[1];
  const float* xv = (const float*)d_in[2];
  const float* co = (const float*)d_in[3];
  const float* wq = (const float*)d_in[4];
  const float* bq = (const float*)d_in[5];
  const float* wk = (const float*)d_in[6];
  const float* bk = (const float*)d_in[7];
  const float* wv = (const float*)d_in[8];
  const float* bv = (const float*)d_in[9];
  const float* sw = (const float*)d_in[10];

  float* out = (float*)d_out;
  float* attn = out + NX;
  _Float16* scratch = (_Float16*)d_out;

  _Float16* qh = (_Float16*)d_ws;
  _Float16* ql = qh + NX;
  _Float16* kh = ql + NX;
  _Float16* kl = kh + NX;
  _Float16* vT = kl + NX;
  _Float16* a16 = qh;

  k_split<<<dim3(2048), 256, 0, stream>>>(xq, xk, xv, wq, wk, wv, scratch);
  k_proj8p<<<dim3(3, 3, 64), 512, 0, stream>>>(scratch, bq, bk, bv, qh, ql, kh,
                                               kl, vT);
  k_scores8p<<<dim3(8, 8, 8), 512, 0, stream>>>(qh, ql, kh, kl, co, sw, attn);
  k_rowsoft<<<dim3(4096), 256, 0, stream>>>(attn, a16);
  k_pv16<<<dim3(6, 16, 8), 256, 0, stream>>>(a16, vT, out);
}

// Round 9
// 482.624 us; speedup vs baseline: 1.5365x; 1.5365x over previous
//
#include <hip/hip_runtime.h>
#include <stdint.h>

// ---------------------------------------------------------------------------
// RichAttention: out = softmax(QK^T - w*cdist(coords)) @ V, attn also output.
// B=8, S=2048, H=768, fp32 in/out.
// R9 = R7 verbatim (505us proven) + XCD-aware bijective block swizzle on
// k_scores8p and k_pv16 ONLY. k_proj = R6/R7 128^2 body (8-phase port of proj
// failed in R8: grid too small/imbalanced for the 256^2 structure).
// ---------------------------------------------------------------------------

typedef _Float16 half8 __attribute__((ext_vector_type(8)));
typedef _Float16 half4v __attribute__((ext_vector_type(4)));
typedef float f32x4 __attribute__((ext_vector_type(4)));

#define DEVI static __device__ __forceinline__

constexpr int B_ = 8, S_ = 2048, H_ = 768;
constexpr long NX = (long)B_ * S_ * H_;   // 12,582,912
constexpr long NW = (long)H_ * H_;        // 589,824
constexpr long ATT = (long)B_ * S_ * S_;  // 33,554,432

// ---- async global->LDS, 16B per lane --------------------------------------
DEVI void glds16(const void* g, void* l) {
  __builtin_amdgcn_global_load_lds(
      (const __attribute__((address_space(1))) uint32_t*)g,
      (__attribute__((address_space(3))) uint32_t*)l, 16, 0, 0);
}

// Stage a [128][32]-fp16 tile (8KB). LDS slot (r,c) holds global chunk
// c ^ ((r>>1)&3). 256 threads x 2 units.
DEVI void stage_tile(const _Float16* gbase, int rowStride, _Float16* lds, int tid) {
#pragma unroll
  for (int seg = 0; seg < 2; ++seg) {
    int u = seg * 256 + tid;
    int r = u >> 2, c = u & 3;
    int sc = c ^ ((r >> 1) & 3);
    glds16(gbase + (long)r * rowStride + sc * 8, lds + ((u & ~63) << 3));
  }
}

// MFMA 16x16x32 A/B fragment read (undoes the chunk swizzle).
DEVI half8 frag(const _Float16* lds, int m0, int lane) {
  int row = m0 + (lane & 15);
  int c = (lane >> 4) ^ ((row >> 1) & 3);
  return *(const half8*)(lds + row * 32 + c * 8);
}

// ---------------------------------------------------------------------------
// K0: split. Xq,Xk -> hi/lo; Xv -> hi only; Wq,Wk -> hi/lo; Wv -> hi only.
// ---------------------------------------------------------------------------
__global__ __launch_bounds__(256) void k_split(
    const float* __restrict__ xq, const float* __restrict__ xk,
    const float* __restrict__ xv, const float* __restrict__ wq,
    const float* __restrict__ wk, const float* __restrict__ wv,
    _Float16* __restrict__ dst) {
  const long NX4 = NX / 4, NW4 = NW / 4, TOT = 3 * NX4 + 3 * NW4;
  for (long u = (long)blockIdx.x * blockDim.x + threadIdx.x; u < TOT;
       u += (long)gridDim.x * blockDim.x) {
    const float4* src;
    _Float16 *dh, *dl;
    bool wantLo = true;
    long idx;
    if (u < 3 * NX4) {
      int z = (u >= 2 * NX4) ? 2 : (u >= NX4) ? 1 : 0;
      idx = u - (long)z * NX4;
      src = (const float4*)(z == 0 ? xq : z == 1 ? xk : xv);
      dh = dst + (long)z * 2 * NX;
      dl = dh + NX;
      wantLo = (z < 2);
    } else {
      long t = u - 3 * NX4;
      int z = (t >= 2 * NW4) ? 2 : (t >= NW4) ? 1 : 0;
      idx = t - (long)z * NW4;
      src = (const float4*)(z == 0 ? wq : z == 1 ? wk : wv);
      dh = dst + 5 * NX + (long)z * 2 * NW;
      dl = dh + NW;
      wantLo = (z < 2);
    }
    float4 x = src[idx];
    half4v hi, lo;
    hi[0] = (_Float16)x.x; lo[0] = (_Float16)(x.x - (float)hi[0]);
    hi[1] = (_Float16)x.y; lo[1] = (_Float16)(x.y - (float)hi[1]);
    hi[2] = (_Float16)x.z; lo[2] = (_Float16)(x.z - (float)hi[2]);
    hi[3] = (_Float16)x.w; lo[3] = (_Float16)(x.w - (float)hi[3]);
    *(half4v*)(dh + idx * 4) = hi;
    if (wantLo) *(half4v*)(dl + idx * 4) = lo;
  }
}

// ---------------------------------------------------------------------------
// K1: projections Y = X @ W^T + b.  [verbatim R1/R6/R7 body]
// ---------------------------------------------------------------------------
__global__ __launch_bounds__(256, 2) void k_proj(
    const _Float16* __restrict__ scratch, const float* __restrict__ bq,
    const float* __restrict__ bk, const float* __restrict__ bv,
    _Float16* __restrict__ qh, _Float16* __restrict__ ql,
    _Float16* __restrict__ kh, _Float16* __restrict__ kl,
    _Float16* __restrict__ vT) {
  const int nt = blockIdx.x, mt = blockIdx.y, z = blockIdx.z;
  const int tid = threadIdx.x;
  const bool full = (z < 2);
  const _Float16* Xh = scratch + (long)z * 2 * NX;
  const _Float16* Xl = Xh + NX;
  const _Float16* Wh = scratch + 5 * NX + (long)z * 2 * NW;
  const _Float16* Wl = Wh + NW;
  const float* bias = (z == 0) ? bq : (z == 1) ? bk : bv;

  __shared__ _Float16 sm[2][4][4096];
  f32x4 acc[4][4] = {};

  const _Float16* Ah = Xh + (long)(mt * 128) * H_;
  const _Float16* Al = Xl + (long)(mt * 128) * H_;
  const _Float16* Bh = Wh + (long)(nt * 128) * H_;
  const _Float16* Bl = Wl + (long)(nt * 128) * H_;

  stage_tile(Ah, H_, sm[0][0], tid);
  stage_tile(Bh, H_, sm[0][2], tid);
  if (full) {
    stage_tile(Al, H_, sm[0][1], tid);
    stage_tile(Bl, H_, sm[0][3], tid);
  }
  __syncthreads();

  const int lane = tid & 63, wid = tid >> 6;
  const int wm = (wid >> 1) * 64, wn = (wid & 1) * 64;

  int cur = 0;
  for (int kk = 0; kk < 24; ++kk) {
    if (kk + 1 < 24) {
      int o = (kk + 1) * 32;
      stage_tile(Ah + o, H_, sm[cur ^ 1][0], tid);
      stage_tile(Bh + o, H_, sm[cur ^ 1][2], tid);
      if (full) {
        stage_tile(Al + o, H_, sm[cur ^ 1][1], tid);
        stage_tile(Bl + o, H_, sm[cur ^ 1][3], tid);
      }
    }
    half8 ah[4], bh[4];
#pragma unroll
    for (int i = 0; i < 4; ++i) ah[i] = frag(sm[cur][0], wm + i * 16, lane);
#pragma unroll
    for (int j = 0; j < 4; ++j) bh[j] = frag(sm[cur][2], wn + j * 16, lane);
#pragma unroll
    for (int i = 0; i < 4; ++i)
#pragma unroll
      for (int j = 0; j < 4; ++j)
        acc[i][j] = __builtin_amdgcn_mfma_f32_16x16x32_f16(ah[i], bh[j],
                                                           acc[i][j], 0, 0, 0);
    if (full) {
      half8 al[4], bl[4];
#pragma unroll
      for (int i = 0; i < 4; ++i) al[i] = frag(sm[cur][1], wm + i * 16, lane);
#pragma unroll
      for (int j = 0; j < 4; ++j) bl[j] = frag(sm[cur][3], wn + j * 16, lane);
#pragma unroll
      for (int i = 0; i < 4; ++i)
#pragma unroll
        for (int j = 0; j < 4; ++j) {
          acc[i][j] = __builtin_amdgcn_mfma_f32_16x16x32_f16(ah[i], bl[j],
                                                             acc[i][j], 0, 0, 0);
          acc[i][j] = __builtin_amdgcn_mfma_f32_16x16x32_f16(al[i], bh[j],
                                                             acc[i][j], 0, 0, 0);
        }
    }
    __syncthreads();
    cur ^= 1;
  }

  _Float16* oh = (z == 0) ? qh : kh;
  _Float16* ol = (z == 0) ? ql : kl;
#pragma unroll
  for (int i = 0; i < 4; ++i) {
    int m_t = wm + i * 16 + ((lane >> 4) << 2);
#pragma unroll
    for (int j = 0; j < 4; ++j) {
      int n_t = wn + j * 16 + (lane & 15);
      int gn = nt * 128 + n_t;
      float bs = bias[gn];
      if (full) {
#pragma unroll
        for (int r = 0; r < 4; ++r) {
          long gm = (long)mt * 128 + m_t + r;
          float y = acc[i][j][r] + bs;
          _Float16 hi = (_Float16)y;
          oh[gm * H_ + gn] = hi;
          ol[gm * H_ + gn] = (_Float16)(y - (float)hi);
        }
      } else {
        int gmI = mt * 128 + m_t;
        int bb = gmI >> 11, t0 = gmI & 2047;
        half4v pk;
#pragma unroll
        for (int r = 0; r < 4; ++r) pk[r] = (_Float16)(acc[i][j][r] + bs);
        *(half4v*)&vT[((long)bb * H_ + gn) * S_ + t0] = pk;
      }
    }
  }
}

// ---------------------------------------------------------------------------
// K2: raw scores = q.k (3-term) - w*dist. 8-phase schedule [R7-proven] +
// XCD swizzle (512 blocks -> one batch per XCD; bijective, 512%8==0).
// ---------------------------------------------------------------------------
__global__ __launch_bounds__(512, 2) void k_scores8p(
    const _Float16* __restrict__ qh, const _Float16* __restrict__ ql,
    const _Float16* __restrict__ kh_, const _Float16* __restrict__ kl_,
    const float* __restrict__ coords, const float* __restrict__ sw,
    float* __restrict__ attn) {
  int bid = blockIdx.x + 8 * blockIdx.y + 64 * blockIdx.z;
  int swz = (bid & 7) * 64 + (bid >> 3);  // bijective: XCD id -> batch
  const int nt = swz & 7, mt = (swz >> 3) & 7, b = swz >> 6;
  const int tid = threadIdx.x, lane = tid & 63, wid = tid >> 6;
  const int wr = wid >> 2, wc = wid & 3;

  __shared__ _Float16 lds[2][2][2][8192];  // [slot][khalf][A,B][256*32]
  __shared__ float cco[4][256];

  if (tid < 256) {
    long gi = (long)b * S_ + mt * 256 + tid;
    cco[0][tid] = coords[gi * 2 + 0];
    cco[1][tid] = coords[gi * 2 + 1];
  } else {
    int t = tid - 256;
    long gj = (long)b * S_ + nt * 256 + t;
    cco[2][t] = coords[gj * 2 + 0];
    cco[3][t] = coords[gj * 2 + 1];
  }
  const float w = sw[0];

  const long aoff = ((long)b * S_ + mt * 256) * H_;
  const long boff = ((long)b * S_ + nt * 256) * H_;

  long goff[2];
  int loff[2];
#pragma unroll
  for (int seg = 0; seg < 2; ++seg) {
    int u = seg * 512 + tid;
    int r = u >> 2, c = u & 3;
    int sc = c ^ ((r >> 1) & 3);
    goff[seg] = (long)r * H_ + sc * 8;
    loff[seg] = (u & ~63) << 3;
  }

  f32x4 acc[8][4] = {};

  auto stage_half = [&](int h) {
    int th = h >> 2, kind = h & 3;
    int khf = kind >> 1, mx = kind & 1;
    int term = th % 3;
    long ko = (long)(th / 3) * 64 + khf * 32;
    const _Float16* src = mx ? ((term == 1 ? kl_ : kh_) + boff + ko)
                             : ((term == 2 ? ql : qh) + aoff + ko);
    _Float16* dst = &lds[th & 1][khf][mx][0];
    glds16(src + goff[0], dst + loff[0]);
    glds16(src + goff[1], dst + loff[1]);
  };

  half8 bf[4];

  auto phase = [&](int slot, int kh2, int mh, int hst, int vm) {
    const _Float16* A = &lds[slot][kh2][0][0];
    const _Float16* Bt = &lds[slot][kh2][1][0];
    half8 af[4];
    if (mh == 0) {
#pragma unroll
      for (int j = 0; j < 4; ++j) bf[j] = frag(Bt, wc * 64 + j * 16, lane);
    }
#pragma unroll
    for (int i = 0; i < 4; ++i)
      af[i] = frag(A, wr * 128 + mh * 64 + i * 16, lane);
    if (hst >= 0) stage_half(hst);
    if (vm == 6) asm volatile("s_waitcnt vmcnt(6)" ::: "memory");
    else if (vm == 0) asm volatile("s_waitcnt vmcnt(0)" ::: "memory");
    __builtin_amdgcn_s_barrier();
    asm volatile("s_waitcnt lgkmcnt(0)" ::: "memory");
    __builtin_amdgcn_sched_barrier(0);
    __builtin_amdgcn_s_setprio(1);
#pragma unroll
    for (int i = 0; i < 4; ++i)
#pragma unroll
      for (int j = 0; j < 4; ++j)
        acc[mh * 4 + i][j] = __builtin_amdgcn_mfma_f32_16x16x32_f16(
            af[i], bf[j], acc[mh * 4 + i][j], 0, 0, 0);
    __builtin_amdgcn_s_setprio(0);
    asm volatile("" ::: "memory");
    __builtin_amdgcn_s_barrier();
  };

#pragma unroll
  for (int h = 0; h < 7; ++h) stage_half(h);
  asm volatile("s_waitcnt vmcnt(6)" ::: "memory");
  __builtin_amdgcn_s_barrier();

#pragma unroll 1
  for (int t = 0; t < 34; ++t) {
    const int slot = t & 1, P = 4 * t;
    phase(slot, 0, 0, P + 7, -1);
    phase(slot, 0, 1, P + 8, -1);
    phase(slot, 1, 0, P + 9, -1);
    phase(slot, 1, 1, P + 10, 6);
  }
  phase(0, 0, 0, 143, -1);
  phase(0, 0, 1, -1, -1);
  phase(0, 1, 0, -1, -1);
  phase(0, 1, 1, -1, 0);
  phase(1, 0, 0, -1, -1);
  phase(1, 0, 1, -1, -1);
  phase(1, 1, 0, -1, -1);
  phase(1, 1, 1, -1, -1);

#pragma unroll
  for (int mi = 0; mi < 8; ++mi) {
    int m_t = wr * 128 + mi * 16 + ((lane >> 4) << 2);
#pragma unroll
    for (int j = 0; j < 4; ++j) {
      int n_t = wc * 64 + j * 16 + (lane & 15);
      float cjx = cco[2][n_t], cjy = cco[3][n_t];
      long rowbase = ((long)b * S_ + mt * 256 + m_t) * S_ + nt * 256 + n_t;
#pragma unroll
      for (int r = 0; r < 4; ++r) {
        float dx = cco[0][m_t + r] - cjx;
        float dy = cco[1][m_t + r] - cjy;
        float d = sqrtf(fmaxf(fmaf(dx, dx, dy * dy), 1e-12f));
        attn[rowbase + (long)r * S_] = acc[mi][j][r] - w * d;
      }
    }
  }
}

// ---------------------------------------------------------------------------
// K2b: row softmax in place (fp32) + normalized fp16 copy for k_pv16.
// ---------------------------------------------------------------------------
__global__ __launch_bounds__(256) void k_rowsoft(float* __restrict__ attn,
                                                 _Float16* __restrict__ a16) {
  const int wid = threadIdx.x >> 6, lane = threadIdx.x & 63;
  long row = (long)blockIdx.x * 4 + wid;
  float* p = attn + row * S_;
  _Float16* p16 = a16 + row * S_;
  float4 v[8];
#pragma unroll
  for (int i = 0; i < 8; ++i) v[i] = ((const float4*)p)[i * 64 + lane];
  float m = -3.4e38f;
#pragma unroll
  for (int i = 0; i < 8; ++i)
    m = fmaxf(m, fmaxf(fmaxf(v[i].x, v[i].y), fmaxf(v[i].z, v[i].w)));
#pragma unroll
  for (int o = 32; o > 0; o >>= 1) m = fmaxf(m, __shfl_xor(m, o));
  float l = 0.f;
#pragma unroll
  for (int i = 0; i < 8; ++i) {
    v[i].x = __expf(v[i].x - m);
    v[i].y = __expf(v[i].y - m);
    v[i].z = __expf(v[i].z - m);
    v[i].w = __expf(v[i].w - m);
    l += (v[i].x + v[i].y) + (v[i].z + v[i].w);
  }
#pragma unroll
  for (int o = 32; o > 0; o >>= 1) l += __shfl_xor(l, o);
  const float rl = 1.0f / l;
#pragma unroll
  for (int i = 0; i < 8; ++i) {
    v[i].x *= rl; v[i].y *= rl; v[i].z *= rl; v[i].w *= rl;
    ((float4*)p)[i * 64 + lane] = v[i];
    half4v h = {(_Float16)v[i].x, (_Float16)v[i].y, (_Float16)v[i].z,
                (_Float16)v[i].w};
    ((half4v*)p16)[i * 64 + lane] = h;
  }
}

// ---------------------------------------------------------------------------
// K3: out = a16 @ vT^T. Pure global_load_lds fp16 pipeline, K=2048.
// XCD swizzle: 768 blocks -> 96/XCD = one batch per XCD (768%8==0).
// ---------------------------------------------------------------------------
__global__ __launch_bounds__(256, 2) void k_pv16(
    const _Float16* __restrict__ a16, const _Float16* __restrict__ vT,
    float* __restrict__ outp) {
  int bid = blockIdx.x + 6 * blockIdx.y + 96 * blockIdx.z;
  int swz = (bid & 7) * 96 + (bid >> 3);
  const int nt = swz % 6, mt = (swz / 6) & 15, b = swz / 96;
  const int tid = threadIdx.x, lane = tid & 63, wid = tid >> 6;
  const int wm = (wid >> 1) * 64, wn = (wid & 1) * 64;
  __shared__ _Float16 sm[2][2][4096];
  f32x4 acc[4][4] = {};
  const _Float16* Ab = a16 + ((long)b * S_ + mt * 128) * S_;
  const _Float16* Bb = vT + ((long)b * H_ + nt * 128) * S_;

  stage_tile(Ab, S_, sm[0][0], tid);
  stage_tile(Bb, S_, sm[0][1], tid);
  __syncthreads();

  int cur = 0;
  for (int kk = 0; kk < 64; ++kk) {
    if (kk + 1 < 64) {
      stage_tile(Ab + (kk + 1) * 32, S_, sm[cur ^ 1][0], tid);
      stage_tile(Bb + (kk + 1) * 32, S_, sm[cur ^ 1][1], tid);
    }
    half8 ah[4], bh[4];
#pragma unroll
    for (int i = 0; i < 4; ++i) ah[i] = frag(sm[cur][0], wm + i * 16, lane);
#pragma unroll
    for (int j = 0; j < 4; ++j) bh[j] = frag(sm[cur][1], wn + j * 16, lane);
#pragma unroll
    for (int i = 0; i < 4; ++i)
#pragma unroll
      for (int j = 0; j < 4; ++j)
        acc[i][j] = __builtin_amdgcn_mfma_f32_16x16x32_f16(ah[i], bh[j],
                                                           acc[i][j], 0, 0, 0);
    __syncthreads();
    cur ^= 1;
  }

#pragma unroll
  for (int i = 0; i < 4; ++i) {
    int m_t = wm + i * 16 + ((lane >> 4) << 2);
#pragma unroll
    for (int j = 0; j < 4; ++j) {
      int n_t = wn + j * 16 + (lane & 15);
      int h = nt * 128 + n_t;
      long rowbase = (long)b * S_ + mt * 128 + m_t;
#pragma unroll
      for (int r = 0; r < 4; ++r) outp[(rowbase + r) * H_ + h] = acc[i][j][r];
    }
  }
}

// ---------------------------------------------------------------------------
extern "C" void kernel_launch(void* const* d_in, const int* in_sizes, int n_in,
                              void* d_out, int out_size, void* d_ws,
                              size_t ws_size, hipStream_t stream) {
  const float* xq = (const float*)d_in[0];
  const float* xk = (const float*)d_in[1];
  const float* xv = (const float*)d_in[2];
  const float* co = (const float*)d_in[3];
  const float* wq = (const float*)d_in[4];
  const float* bq = (const float*)d_in[5];
  const float* wk = (const float*)d_in[6];
  const float* bk = (const float*)d_in[7];
  const float* wv = (const float*)d_in[8];
  const float* bv = (const float*)d_in[9];
  const float* sw = (const float*)d_in[10];

  float* out = (float*)d_out;
  float* attn = out + NX;
  _Float16* scratch = (_Float16*)d_out;

  _Float16* qh = (_Float16*)d_ws;
  _Float16* ql = qh + NX;
  _Float16* kh = ql + NX;
  _Float16* kl = kh + NX;
  _Float16* vT = kl + NX;
  _Float16* a16 = qh;

  k_split<<<dim3(2048), 256, 0, stream>>>(xq, xk, xv, wq, wk, wv, scratch);
  k_proj<<<dim3(6, 128, 3), 256, 0, stream>>>(scratch, bq, bk, bv, qh, ql, kh,
                                              kl, vT);
  k_scores8p<<<dim3(8, 8, 8), 512, 0, stream>>>(qh, ql, kh, kl, co, sw, attn);
  k_rowsoft<<<dim3(4096), 256, 0, stream>>>(attn, a16);
  k_pv16<<<dim3(6, 16, 8), 256, 0, stream>>>(a16, vT, out);
}